// Round 6
// baseline (481.934 us; speedup 1.0000x reference)
//
#include <hip/hip_runtime.h>
#include <hip/hip_bf16.h>
#include <hip/hip_cooperative_groups.h>

namespace cg = cooperative_groups;

#define NN 1024
#define HID 128
#define NHEADS 4
#define HDD 32
#define NL 3

// ---- ws layout (float-word units) ----
constexpr int OFF_CONV = 16;
constexpr int OFF_NF   = OFF_CONV;            // 3072
constexpr int OFF_WP   = OFF_NF  + 3072;      // 384
constexpr int OFF_BP   = OFF_WP  + 384;       // 128
constexpr int OFF_WL   = OFF_BP  + 128;       // 49152
constexpr int OFF_WR   = OFF_WL  + 49152;     // 49152
constexpr int OFF_WVW  = OFF_WR  + 49152;     // 49152
constexpr int OFF_ATT  = OFF_WVW + 49152;     // 96
constexpr int OFF_GAM  = OFF_ATT + 96;        // 384
constexpr int OFF_BET  = OFF_GAM + 384;       // 384
constexpr int OFF_WN1  = OFF_BET + 384;       // 8192
constexpr int OFF_BN1  = OFF_WN1 + 8192;      // 64
constexpr int OFF_WN2  = OFF_BN1 + 64;        // 64
constexpr int OFF_BN2  = OFF_WN2 + 64;        // 1
constexpr int OFF_WD1  = OFF_BN2 + 1;         // 8192
constexpr int OFF_BD1  = OFF_WD1 + 8192;      // 64
constexpr int OFF_WD2  = OFF_BD1 + 64;        // 128
constexpr int OFF_BD2  = OFF_WD2 + 128;       // 2
constexpr int OFF_WV1  = OFF_BD2 + 2;         // 8192
constexpr int OFF_BV1  = OFF_WV1 + 8192;      // 64
constexpr int OFF_WV2  = OFF_BV1 + 64;        // 64
constexpr int OFF_BV2  = OFF_WV2 + 64;        // 1
constexpr int OFF_CONV_END = OFF_BV2 + 1;
constexpr int CONV_TOTAL = OFF_CONV_END - OFF_CONV;
constexpr int OFF_MASK = 176960;              // 1024*32 uint32 words
constexpr int OFF_H    = OFF_MASK + NN*32;
constexpr int OFF_WLH  = OFF_H   + NN*HID;    // normal [i][128]
constexpr int OFF_WRH  = OFF_WLH + NN*HID;    // TRANSPOSED [dq=32][j=1024][4]
constexpr int OFF_WVH  = OFF_WRH + NN*HID;    // TRANSPOSED [dq=32][j=1024][4]
constexpr int OFF_CL   = OFF_WVH + NN*HID;    // [h][i]  0.6*att.wl
constexpr int OFF_CR   = OFF_CL  + NHEADS*NN; // [h][j]  0.6*att.wr
constexpr int OFF_PART = OFF_CR  + NHEADS*NN; // [block][128] pooled partials

__device__ __forceinline__ float bf2f(unsigned short u) {
    return __uint_as_float(((unsigned)u) << 16);
}
__device__ __forceinline__ void store_out(void* out, int idx, float v, bool bf) {
    if (bf) {
        unsigned u = __float_as_uint(v);
        unsigned r = (u + 0x7FFFu + ((u >> 16) & 1u)) >> 16;
        ((unsigned short*)out)[idx] = (unsigned short)r;
    } else {
        ((float*)out)[idx] = v;
    }
}
__device__ __forceinline__ float ldraw(const void* p, int idx, bool bf) {
    return bf ? bf2f(((const unsigned short*)p)[idx]) : ((const float*)p)[idx];
}
// per-wave dtype sniff: fp32 normals have exponent field in [110,140];
// packed bf16 pairs viewed as fp32 essentially never do. Call from ALL lanes.
__device__ __forceinline__ bool detect_bf(const unsigned* nf) {
    unsigned w = nf[threadIdx.x & 63];
    int e = (int)((w >> 23) & 0xFFu);
    unsigned long long b = __ballot(e >= 110 && e <= 140);
    return __popcll(b) < 32;
}

struct P21 { const void* p[21]; };
__device__ const int g_sizes[21] = {3072,384,128,49152,49152,49152,96,384,384,
                                    8192,64,64,1,8192,64,128,2,8192,64,64,1};
__device__ const int g_dsts[21] = {OFF_NF,OFF_WP,OFF_BP,OFF_WL,OFF_WR,OFF_WVW,OFF_ATT,
                                   OFF_GAM,OFF_BET,OFF_WN1,OFF_BN1,OFF_WN2,OFF_BN2,
                                   OFF_WD1,OFF_BD1,OFF_WD2,OFF_BD2,OFF_WV1,OFF_BV1,
                                   OFF_WV2,OFF_BV2};

// ================= ONE cooperative kernel: 256 blocks x 512 threads =========
// Eliminates 7 kernel boundaries (launch+drain+tail each) from the r5
// structure; phases separated by grid.sync(). Per-phase inner loops are the
// r4/r5-verified ones; only thread->work mappings were re-folded to 256x512.
__global__ __launch_bounds__(512) void k_mega(P21 in, const void* adj,
                                              const unsigned* nf, float* ws,
                                              void* out) {
    cg::grid_group grid = cg::this_grid();
    const bool bf = detect_bf(nf);
    const int b = blockIdx.x, t = threadIdx.x;
    const int lane = t & 63;
    const int i0 = b * 4;                 // this block owns nodes i0..i0+3

    __shared__ union U {
        float hs[4][HID];                 // mm3 phase
        struct {                          // attn phase (~68.6 KB)
            unsigned mrow[4][32];
            float ebuf[8][64][33];
            float invs[4][4];
            float agg[4][HID];
            float red2[4][2][2];
        } at;
        struct {                          // post phase
            float hrow[4][HID];
            float pooled[HID];
        } po;
    } sh;

    // ---------- P0: param convert | adj->bitmask | h0 (independent) ----------
    for (int g = b * 512 + t; g < CONV_TOTAL; g += 256 * 512) {
        int rem = g, s = 0;
        while (s < 21 && rem >= g_sizes[s]) { rem -= g_sizes[s]; s++; }
        if (s < 21) ws[g_dsts[s] + rem] = ldraw(in.p[s], rem, bf);
    }
    {   // adj bitmask: row n = t>>7 of this block's 4; wave-pair covers 16 segs
        unsigned* mask = (unsigned*)(ws + OFF_MASK);
        int n = t >> 7, wvr = (t >> 6) & 1;
        int i = i0 + n;
        #pragma unroll
        for (int q = 0; q < 8; q++) {
            int seg = wvr * 8 + q;
            float v = ldraw(adj, i * NN + seg * 64 + lane, bf);
            unsigned long long bl = __ballot(v > 0.5f);
            if (lane == 0) {
                mask[i * 32 + seg * 2]     = (unsigned)bl;
                mask[i * 32 + seg * 2 + 1] = (unsigned)(bl >> 32);
            }
        }
    }
    {   // h0 = relu(nf @ Wp + bp): exactly one element per thread (131072)
        int g = b * 512 + t;
        int i = g >> 7, c = g & 127;
        float a = ldraw(in.p[2], c, bf);
        #pragma unroll
        for (int k = 0; k < 3; k++)
            a += ldraw(in.p[0], i * 3 + k, bf) * ldraw(in.p[1], k * HID + c, bf);
        ws[OFF_H + i * HID + c] = fmaxf(a, 0.0f);
    }
    grid.sync();

    // ============================ layers ============================
    for (int l = 0; l < NL; l++) {
        // ---------- P1: mm3 — wlh (+cl), wrT (+cr), wvT for own 4 nodes ------
        {
            int gq = t >> 7, c = t & 127;     // node-in-block, output column
            sh.hs[gq][c] = ws[OFF_H + (i0 + gq) * HID + c];
            __syncthreads();
            #pragma unroll 1
            for (int which = 0; which < 3; which++) {
                int woff = (which == 0) ? OFF_WL : (which == 1) ? OFF_WR : OFF_WVW;
                const float* W = ws + woff + l * HID * HID;
                float a0 = 0.f, a1 = 0.f;
                #pragma unroll 8
                for (int k = 0; k < HID; k += 2) {
                    a0 += sh.hs[gq][k]     * W[k * HID + c];
                    a1 += sh.hs[gq][k + 1] * W[(k + 1) * HID + c];
                }
                float a = a0 + a1;
                if (which == 0) {
                    ws[OFF_WLH + (i0 + gq) * HID + c] = a;
                    float att = ws[OFF_ATT + l * HDD + (c & 31)];
                    float s = att * a;
                    #pragma unroll
                    for (int off = 1; off < 32; off <<= 1) s += __shfl_xor(s, off, 64);
                    if ((c & 31) == 0) ws[OFF_CL + (c >> 5) * NN + (i0 + gq)] = 0.6f * s;
                } else {
                    int doff = (which == 1) ? OFF_WRH : OFF_WVH;
                    ws[doff + (c >> 2) * (NN * 4) + (i0 + gq) * 4 + (c & 3)] = a;
                    if (which == 1) {
                        float att = ws[OFF_ATT + l * HDD + (c & 31)];
                        float s = att * a;
                        #pragma unroll
                        for (int off = 1; off < 32; off <<= 1) s += __shfl_xor(s, off, 64);
                        if ((c & 31) == 0) ws[OFF_CR + (c >> 5) * NN + (i0 + gq)] = 0.6f * s;
                    }
                }
            }
        }
        grid.sync();

        // ---------- P2: attn (r4-verified body) ----------
        {
            int wv = t >> 6;
            int h  = __builtin_amdgcn_readfirstlane(wv & 3);
            int pr = __builtin_amdgcn_readfirstlane(wv >> 2);
            int iA = i0 + 2 * pr, iB = iA + 1;

            if (t < 128) sh.at.mrow[t >> 5][t & 31] =
                ((const unsigned*)(ws + OFF_MASK))[i0 * 32 + t];
            __syncthreads();

            unsigned mbA = 0, mbB = 0;
            #pragma unroll
            for (int jc = 0; jc < 16; jc++) {
                int wi = jc * 2 + (lane >> 5);
                mbA |= ((sh.at.mrow[2 * pr][wi]     >> (lane & 31)) & 1u) << jc;
                mbB |= ((sh.at.mrow[2 * pr + 1][wi] >> (lane & 31)) & 1u) << jc;
            }

            float att_r[32], wlA[32], wlB[32];
            const float* attp = ws + OFF_ATT + l * HDD;
            const float* wlpA = ws + OFF_WLH + iA * HID + h * HDD;
            const float* wlpB = ws + OFF_WLH + iB * HID + h * HDD;
            #pragma unroll
            for (int d = 0; d < 32; d++) {
                att_r[d] = 0.4f * attp[d];
                wlA[d] = wlpA[d];
                wlB[d] = wlpB[d];
            }
            float clA = ws[OFF_CL + h * NN + iA];
            float clB = ws[OFF_CL + h * NN + iB];

            const float* wrT = ws + OFF_WRH + h * 8 * (NN * 4) + lane * 4;
            const float* wvT = ws + OFF_WVH + h * 8 * (NN * 4) + lane * 4;
            const float* crp = ws + OFF_CR + h * NN;

            float mA = -1e30f, mB = -1e30f;
            #pragma unroll 1
            for (int jc = 0; jc < 16; jc++) {
                float cr6 = crp[jc * 64 + lane];
                float dA = 0.f, dB = 0.f;
                #pragma unroll
                for (int dq = 0; dq < 8; dq++) {
                    float4 w4 = *(const float4*)(wrT + dq * (NN * 4) + jc * 256);
                    dA = fmaf(att_r[dq*4+0], fabsf(wlA[dq*4+0] + w4.x), dA);
                    dB = fmaf(att_r[dq*4+0], fabsf(wlB[dq*4+0] + w4.x), dB);
                    dA = fmaf(att_r[dq*4+1], fabsf(wlA[dq*4+1] + w4.y), dA);
                    dB = fmaf(att_r[dq*4+1], fabsf(wlB[dq*4+1] + w4.y), dB);
                    dA = fmaf(att_r[dq*4+2], fabsf(wlA[dq*4+2] + w4.z), dA);
                    dB = fmaf(att_r[dq*4+2], fabsf(wlB[dq*4+2] + w4.z), dB);
                    dA = fmaf(att_r[dq*4+3], fabsf(wlA[dq*4+3] + w4.w), dA);
                    dB = fmaf(att_r[dq*4+3], fabsf(wlB[dq*4+3] + w4.w), dB);
                }
                float eA = (clA + cr6) + dA; eA = ((mbA >> jc) & 1u) ? eA : -1e9f;
                float eB = (clB + cr6) + dB; eB = ((mbB >> jc) & 1u) ? eB : -1e9f;
                sh.at.ebuf[wv][lane][jc]      = eA;
                sh.at.ebuf[wv][lane][16 + jc] = eB;
                mA = fmaxf(mA, eA);
                mB = fmaxf(mB, eB);
            }
            #pragma unroll
            for (int off = 32; off > 0; off >>= 1) {
                mA = fmaxf(mA, __shfl_xor(mA, off, 64));
                mB = fmaxf(mB, __shfl_xor(mB, off, 64));
            }

            float accA[32], accB[32];
            #pragma unroll
            for (int d = 0; d < 32; d++) { accA[d] = 0.f; accB[d] = 0.f; }
            float lsA = 0.f, lsB = 0.f;
            #pragma unroll 1
            for (int jc = 0; jc < 16; jc++) {
                float peA = __expf(sh.at.ebuf[wv][lane][jc]      - mA);
                float peB = __expf(sh.at.ebuf[wv][lane][16 + jc] - mB);
                lsA += peA; lsB += peB;
                #pragma unroll
                for (int dq = 0; dq < 8; dq++) {
                    float4 v4 = *(const float4*)(wvT + dq * (NN * 4) + jc * 256);
                    accA[dq*4+0] = fmaf(peA, v4.x, accA[dq*4+0]);
                    accB[dq*4+0] = fmaf(peB, v4.x, accB[dq*4+0]);
                    accA[dq*4+1] = fmaf(peA, v4.y, accA[dq*4+1]);
                    accB[dq*4+1] = fmaf(peB, v4.y, accB[dq*4+1]);
                    accA[dq*4+2] = fmaf(peA, v4.z, accA[dq*4+2]);
                    accB[dq*4+2] = fmaf(peB, v4.z, accB[dq*4+2]);
                    accA[dq*4+3] = fmaf(peA, v4.w, accA[dq*4+3]);
                    accB[dq*4+3] = fmaf(peB, v4.w, accB[dq*4+3]);
                }
            }
            #pragma unroll
            for (int off = 32; off > 0; off >>= 1) {
                lsA += __shfl_xor(lsA, off, 64);
                lsB += __shfl_xor(lsB, off, 64);
            }
            if (lane == 0) {
                sh.at.invs[2 * pr][h]     = 1.0f / lsA;
                sh.at.invs[2 * pr + 1][h] = 1.0f / lsB;
            }
            __syncthreads();

            float* rbuf = &sh.at.ebuf[0][0][0];
            {   // reduce round 0: node iA
                int reg = pr * 4 + h;
                #pragma unroll
                for (int d = 0; d < 32; d++) rbuf[(reg * 64 + lane) * 33 + d] = accA[d];
                __syncthreads();
                int g = t >> 6, d = lane & 31, half = lane >> 5;
                float s = 0.f;
                #pragma unroll
                for (int lq = 0; lq < 32; lq++) s += rbuf[(g * 64 + half * 32 + lq) * 33 + d];
                s += __shfl_xor(s, 32, 64);
                int node = 2 * (g >> 2), hh = g & 3;
                if (half == 0) sh.at.agg[node][hh * 32 + d] = s * sh.at.invs[node][hh];
                __syncthreads();
            }
            {   // reduce round 1: node iB
                int reg = pr * 4 + h;
                #pragma unroll
                for (int d = 0; d < 32; d++) rbuf[(reg * 64 + lane) * 33 + d] = accB[d];
                __syncthreads();
                int g = t >> 6, d = lane & 31, half = lane >> 5;
                float s = 0.f;
                #pragma unroll
                for (int lq = 0; lq < 32; lq++) s += rbuf[(g * 64 + half * 32 + lq) * 33 + d];
                s += __shfl_xor(s, 32, 64);
                int node = 2 * (g >> 2) + 1, hh = g & 3;
                if (half == 0) sh.at.agg[node][hh * 32 + d] = s * sh.at.invs[node][hh];
                __syncthreads();
            }

            {   // layernorm + residual: node n=t>>7, feature f=t&127
                int n = t >> 7, f = t & 127;
                float agg = sh.at.agg[n][f];
                float s = agg, s2 = agg * agg;
                #pragma unroll
                for (int off = 32; off > 0; off >>= 1) {
                    s  += __shfl_xor(s,  off, 64);
                    s2 += __shfl_xor(s2, off, 64);
                }
                int half = (t >> 6) & 1;
                if (lane == 0) { sh.at.red2[n][half][0] = s; sh.at.red2[n][half][1] = s2; }
                __syncthreads();
                float ts  = sh.at.red2[n][0][0] + sh.at.red2[n][1][0];
                float ts2 = sh.at.red2[n][0][1] + sh.at.red2[n][1][1];
                float mu  = ts  * (1.0f / HID);
                float var = ts2 * (1.0f / HID) - mu * mu;
                float gm = ws[OFF_GAM + l * HID + f];
                float be = ws[OFF_BET + l * HID + f];
                float o = (agg - mu) * rsqrtf(var + 1e-5f) * gm + be;
                ws[OFF_H + (i0 + n) * HID + f] += fmaxf(o, 0.0f);
            }
        }
        grid.sync();
    }

    // ---------- P3: heads for own 4 nodes + pooled partial ----------
    {
        int n = t >> 7, s7 = t & 127;
        sh.po.hrow[n][s7] = ws[OFF_H + (i0 + n) * HID + s7];
        __syncthreads();
        int half = (t >> 6) & 1;     // wave 2n: logits; wave 2n+1: delta
        int tt = lane;
        if (half == 0) {
            float z1 = ws[OFF_BN1 + tt];
            #pragma unroll 8
            for (int k = 0; k < HID; k++) z1 += sh.po.hrow[n][k] * ws[OFF_WN1 + k * 64 + tt];
            z1 = fmaxf(z1, 0.0f);
            float lg = z1 * ws[OFF_WN2 + tt];
            #pragma unroll
            for (int off = 32; off > 0; off >>= 1) lg += __shfl_xor(lg, off, 64);
            if (tt == 0) store_out(out, i0 + n, lg + ws[OFF_BN2], bf);
        } else {
            float zd = ws[OFF_BD1 + tt];
            #pragma unroll 8
            for (int k = 0; k < HID; k++) zd += sh.po.hrow[n][k] * ws[OFF_WD1 + k * 64 + tt];
            zd = fmaxf(zd, 0.0f);
            float d0 = zd * ws[OFF_WD2 + tt * 2 + 0];
            float d1 = zd * ws[OFF_WD2 + tt * 2 + 1];
            #pragma unroll
            for (int off = 32; off > 0; off >>= 1) {
                d0 += __shfl_xor(d0, off, 64);
                d1 += __shfl_xor(d1, off, 64);
            }
            if (tt == 0) {
                store_out(out, NN + (i0 + n) * 2 + 0, d0 + ws[OFF_BD2 + 0], bf);
                store_out(out, NN + (i0 + n) * 2 + 1, d1 + ws[OFF_BD2 + 1], bf);
            }
        }
        if (t < 128) {
            float s = sh.po.hrow[0][t] + sh.po.hrow[1][t]
                    + sh.po.hrow[2][t] + sh.po.hrow[3][t];
            ws[OFF_PART + b * HID + t] = s;
        }
    }
    grid.sync();

    // ---------- P4: value head (block 0 only; deterministic tree) ----------
    if (b == 0) {
        if (t < 128) {
            float p = 0.f;
            #pragma unroll 16
            for (int q = 0; q < 256; q++) p += ws[OFF_PART + q * HID + t];
            sh.po.pooled[t] = p * (1.0f / NN);
        }
        __syncthreads();
        if (t < 64) {
            float z = ws[OFF_BV1 + t], z1 = 0.f;
            #pragma unroll 8
            for (int k = 0; k < HID; k += 2) {
                z  += sh.po.pooled[k]     * ws[OFF_WV1 + k * 64 + t];
                z1 += sh.po.pooled[k + 1] * ws[OFF_WV1 + (k + 1) * 64 + t];
            }
            z = fmaxf(z + z1, 0.0f);
            float pv = z * ws[OFF_WV2 + t];
            #pragma unroll
            for (int off = 32; off > 0; off >>= 1) pv += __shfl_xor(pv, off, 64);
            if (t == 0) store_out(out, 3072, pv + ws[OFF_BV2], bf);
        }
    }
}

extern "C" void kernel_launch(void* const* d_in, const int* in_sizes, int n_in,
                              void* d_out, int out_size, void* d_ws, size_t ws_size,
                              hipStream_t stream) {
    float* ws = (float*)d_ws;
    const unsigned* nf = (const unsigned*)d_in[0];
    const void* adj = d_in[1];

    P21 ptrs;
    const int map[21] = {0,2,3,4,5,6,7,8,9,10,11,12,13,14,15,16,17,18,19,20,21};
    for (int s = 0; s < 21; s++) ptrs.p[s] = d_in[map[s]];

    void* outp = d_out;
    void* kargs[] = { (void*)&ptrs, (void*)&adj, (void*)&nf, (void*)&ws, (void*)&outp };
    hipLaunchCooperativeKernel((const void*)k_mega, dim3(256), dim3(512),
                               kargs, 0, stream);
}

// Round 7
// 296.024 us; speedup vs baseline: 1.6280x; 1.6280x over previous
//
#include <hip/hip_runtime.h>
#include <hip/hip_bf16.h>

#define NN 1024
#define HID 128
#define NHEADS 4
#define HDD 32
#define NL 3

// ---- ws layout (float-word units) ----
constexpr int OFF_CONV = 16;
constexpr int OFF_NF   = OFF_CONV;            // 3072
constexpr int OFF_WP   = OFF_NF  + 3072;      // 384
constexpr int OFF_BP   = OFF_WP  + 384;       // 128
constexpr int OFF_WL   = OFF_BP  + 128;       // 49152
constexpr int OFF_WR   = OFF_WL  + 49152;     // 49152
constexpr int OFF_WVW  = OFF_WR  + 49152;     // 49152
constexpr int OFF_ATT  = OFF_WVW + 49152;     // 96
constexpr int OFF_GAM  = OFF_ATT + 96;        // 384
constexpr int OFF_BET  = OFF_GAM + 384;       // 384
constexpr int OFF_WN1  = OFF_BET + 384;       // 8192
constexpr int OFF_BN1  = OFF_WN1 + 8192;      // 64
constexpr int OFF_WN2  = OFF_BN1 + 64;        // 64
constexpr int OFF_BN2  = OFF_WN2 + 64;        // 1
constexpr int OFF_WD1  = OFF_BN2 + 1;         // 8192
constexpr int OFF_BD1  = OFF_WD1 + 8192;      // 64
constexpr int OFF_WD2  = OFF_BD1 + 64;        // 128
constexpr int OFF_BD2  = OFF_WD2 + 128;       // 2
constexpr int OFF_WV1  = OFF_BD2 + 2;         // 8192
constexpr int OFF_BV1  = OFF_WV1 + 8192;      // 64
constexpr int OFF_WV2  = OFF_BV1 + 64;        // 64
constexpr int OFF_BV2  = OFF_WV2 + 64;        // 1
constexpr int OFF_CONV_END = OFF_BV2 + 1;
constexpr int CONV_TOTAL = OFF_CONV_END - OFF_CONV;
constexpr int CB = (CONV_TOTAL + 255) / 256;  // convert blocks in k_pre
constexpr int OFF_MASK = 176960;              // 1024*32 uint32 words
constexpr int OFF_H    = OFF_MASK + NN*32;
constexpr int OFF_WLH  = OFF_H   + NN*HID;    // normal [i][128]
constexpr int OFF_WRH  = OFF_WLH + NN*HID;    // TRANSPOSED [dq=32][j=1024][4]
constexpr int OFF_WVH  = OFF_WRH + NN*HID;    // TRANSPOSED [dq=32][j=1024][4]
constexpr int OFF_CL   = OFF_WVH + NN*HID;    // [h][i]  0.6*att.wl
constexpr int OFF_CR   = OFF_CL  + NHEADS*NN; // [h][j]  0.6*att.wr

__device__ __forceinline__ float bf2f(unsigned short u) {
    return __uint_as_float(((unsigned)u) << 16);
}
__device__ __forceinline__ void store_out(void* out, int idx, float v, bool bf) {
    if (bf) {
        unsigned u = __float_as_uint(v);
        unsigned r = (u + 0x7FFFu + ((u >> 16) & 1u)) >> 16;
        ((unsigned short*)out)[idx] = (unsigned short)r;
    } else {
        ((float*)out)[idx] = v;
    }
}
__device__ __forceinline__ float ldraw(const void* p, int idx, bool bf) {
    return bf ? bf2f(((const unsigned short*)p)[idx]) : ((const float*)p)[idx];
}
// per-wave dtype sniff: fp32 normals have exponent field in [110,140];
// packed bf16 pairs viewed as fp32 essentially never do. Call from ALL lanes.
__device__ __forceinline__ bool detect_bf(const unsigned* nf) {
    unsigned w = nf[threadIdx.x & 63];
    int e = (int)((w >> 23) & 0xFFu);
    unsigned long long b = __ballot(e >= 110 && e <= 140);
    return __popcll(b) < 32;
}

struct P21 { const void* p[21]; };
__device__ const int g_sizes[21] = {3072,384,128,49152,49152,49152,96,384,384,
                                    8192,64,64,1,8192,64,128,2,8192,64,64,1};
__device__ const int g_dsts[21] = {OFF_NF,OFF_WP,OFF_BP,OFF_WL,OFF_WR,OFF_WVW,OFF_ATT,
                                   OFF_GAM,OFF_BET,OFF_WN1,OFF_BN1,OFF_WN2,OFF_BN2,
                                   OFF_WD1,OFF_BD1,OFF_WD2,OFF_BD2,OFF_WV1,OFF_BV1,
                                   OFF_WV2,OFF_BV2};

// ---- fused prologue: param convert | adj->bitmask | h0  (all independent:
// h0 reads RAW nf/Wp/bp with its own bf16 handling, so no ordering needed) ----
__global__ __launch_bounds__(256) void k_pre(P21 in, const void* adj, const unsigned* nf, float* ws) {
    bool bf = detect_bf(nf);
    int b = blockIdx.x, t = threadIdx.x;
    if (b < CB) {
        // convert all non-adj params to fp32 in ws
        int g = b * 256 + t;
        if (g >= CONV_TOTAL) return;
        int rem = g, s = 0;
        while (s < 21 && rem >= g_sizes[s]) { rem -= g_sizes[s]; s++; }
        if (s >= 21) return;
        ws[g_dsts[s] + rem] = ldraw(in.p[s], rem, bf);
    } else if (b < CB + NN) {
        // adj row -> packed bitmask
        int i = b - CB;
        unsigned* mask = (unsigned*)(ws + OFF_MASK);
        int lane = t & 63, wv = t >> 6;
        #pragma unroll
        for (int q = 0; q < 4; q++) {
            int seg = wv * 4 + q;
            int j = seg * 64 + lane;
            float v = ldraw(adj, i * NN + j, bf);
            unsigned long long bl = __ballot(v > 0.5f);
            if (lane == 0) {
                mask[i * 32 + seg * 2]     = (unsigned)bl;
                mask[i * 32 + seg * 2 + 1] = (unsigned)(bl >> 32);
            }
        }
    } else {
        // h0 = relu(nf @ Wp + bp), raw reads: 2 nodes per block
        int bb = b - CB - NN;
        int i = bb * 2 + (t >> 7), c = t & 127;
        float a = ldraw(in.p[2], c, bf);                     // bp
        #pragma unroll
        for (int k = 0; k < 3; k++)
            a += ldraw(in.p[0], i * 3 + k, bf) * ldraw(in.p[1], k * HID + c, bf);
        ws[OFF_H + i * HID + c] = fmaxf(a, 0.0f);
    }
}

// ---- per layer: wlh = h@Wl (normal + cl), wrh/wvh = h@{Wr,Wv} (transposed + cr) ----
__global__ __launch_bounds__(128) void k_mm3(float* ws, int l) {
    __shared__ float hs[4][HID];
    int c = threadIdx.x, i0 = blockIdx.x * 4, which = blockIdx.y;
    const float* h = ws + OFF_H;
    #pragma unroll
    for (int r = 0; r < 4; r++) hs[r][c] = h[(i0 + r) * HID + c];
    __syncthreads();
    int woff = (which == 0) ? OFF_WL : (which == 1) ? OFF_WR : OFF_WVW;
    const float* W = ws + woff + l * HID * HID;
    float a[4] = {0,0,0,0};
    #pragma unroll 4
    for (int k = 0; k < HID; k++) {
        float w = W[k * HID + c];
        #pragma unroll
        for (int r = 0; r < 4; r++) a[r] += hs[r][k] * w;
    }
    if (which == 0) {
        #pragma unroll
        for (int r = 0; r < 4; r++) ws[OFF_WLH + (i0 + r) * HID + c] = a[r];
        float att = ws[OFF_ATT + l * HDD + (c & 31)];
        #pragma unroll
        for (int r = 0; r < 4; r++) {
            float t = att * a[r];
            #pragma unroll
            for (int off = 1; off < 32; off <<= 1) t += __shfl_xor(t, off, 64);
            if ((c & 31) == 0) ws[OFF_CL + (c >> 5) * NN + (i0 + r)] = 0.6f * t;
        }
    } else {
        int doff = (which == 1) ? OFF_WRH : OFF_WVH;
        // transposed-tiled: element (j, c) -> [c>>2][j][c&3]
        #pragma unroll
        for (int r = 0; r < 4; r++)
            ws[doff + (c >> 2) * (NN * 4) + (i0 + r) * 4 + (c & 3)] = a[r];
        if (which == 1) {
            float att = ws[OFF_ATT + l * HDD + (c & 31)];
            #pragma unroll
            for (int r = 0; r < 4; r++) {
                float t = att * a[r];
                #pragma unroll
                for (int off = 1; off < 32; off <<= 1) t += __shfl_xor(t, off, 64);
                if ((c & 31) == 0) ws[OFF_CR + (c >> 5) * NN + (i0 + r)] = 0.6f * t;
            }
        }
    }
}

// ---- per layer: fused attention, 4-node-tiled, SINGLE-PASS online softmax ----
// Block = 512 threads = 8 waves, 4 NODES per block (grid 256 = 1 block/CU).
// Wave w: head h = w&3, node-pair p = w>>2 -> nodes iA=i0+2p, iB=iA+1.
// ONE 16-iter stream (vs r5's two passes): per-lane online softmax with
// deferred rescale (THR=8). Each lane keeps its own running max m; rescale
// triggers only when e > m+8 (few times, early jc). Final: cross-lane max,
// one end-rescale of acc/lsum, then LDS reduce. Masked edges need no special
// casing: exp(-1e9 - m) underflows to exact 0, and an all-masked lane's
// garbage is annihilated by exp(m_lane - m_global) = 0 at the merge.
// wv loads issued BEFORE the e-computation -> 16 loads in flight, e-compute
// (~260 cyc) covers L2 latency. e-LDS round trip and one barrier removed.
__global__ __launch_bounds__(512) void k_attn(float* ws, int l) {
    int t = threadIdx.x;
    int i0 = blockIdx.x * 4;
    int lane = t & 63;
    int w = t >> 6;
    int h = __builtin_amdgcn_readfirstlane(w & 3);
    int p = __builtin_amdgcn_readfirstlane(w >> 2);
    int iA = i0 + 2 * p, iB = iA + 1;

    __shared__ unsigned mrow[4][32];
    __shared__ float rbuf_s[8][64][33];  // acc-reduce scratch (stride 33, conflict-free)
    __shared__ float invs[4][4];         // [node][head]
    __shared__ float agg_s[4][HID];
    __shared__ float red2[4][2][2];

    if (t < 128) mrow[t >> 5][t & 31] = ((const unsigned*)(ws + OFF_MASK))[i0 * 32 + t];
    __syncthreads();

    // per-lane 16-bit adjacency masks for both nodes: bit jc = adj of j=jc*64+lane
    unsigned mbA = 0, mbB = 0;
    #pragma unroll
    for (int jc = 0; jc < 16; jc++) {
        int wi = jc * 2 + (lane >> 5);
        mbA |= ((mrow[2 * p][wi] >> (lane & 31)) & 1u) << jc;
        mbB |= ((mrow[2 * p + 1][wi] >> (lane & 31)) & 1u) << jc;
    }

    // wave-uniform vectors -> registers (0.4 folded into att)
    float att_r[32], wlA[32], wlB[32];
    const float* attp = ws + OFF_ATT + l * HDD;
    const float* wlpA = ws + OFF_WLH + iA * HID + h * HDD;
    const float* wlpB = ws + OFF_WLH + iB * HID + h * HDD;
    #pragma unroll
    for (int d = 0; d < 32; d++) {
        att_r[d] = 0.4f * attp[d];
        wlA[d] = wlpA[d];
        wlB[d] = wlpB[d];
    }
    float clA = ws[OFF_CL + h * NN + iA];
    float clB = ws[OFF_CL + h * NN + iB];

    const float* wrT = ws + OFF_WRH + h * 8 * (NN * 4) + lane * 4;
    const float* wvT = ws + OFF_WVH + h * 8 * (NN * 4) + lane * 4;
    const float* crp = ws + OFF_CR + h * NN;

    float accA[32], accB[32];
    #pragma unroll
    for (int d = 0; d < 32; d++) { accA[d] = 0.f; accB[d] = 0.f; }
    float lsA = 0.f, lsB = 0.f;
    float mA = -1e30f, mB = -1e30f;

    #pragma unroll 1
    for (int jc = 0; jc < 16; jc++) {
        // issue V loads early; consumed after e/rescale (covers L2 latency)
        float4 v0 = *(const float4*)(wvT + 0 * (NN * 4) + jc * 256);
        float4 v1 = *(const float4*)(wvT + 1 * (NN * 4) + jc * 256);
        float4 v2 = *(const float4*)(wvT + 2 * (NN * 4) + jc * 256);
        float4 v3 = *(const float4*)(wvT + 3 * (NN * 4) + jc * 256);
        float4 v4 = *(const float4*)(wvT + 4 * (NN * 4) + jc * 256);
        float4 v5 = *(const float4*)(wvT + 5 * (NN * 4) + jc * 256);
        float4 v6 = *(const float4*)(wvT + 6 * (NN * 4) + jc * 256);
        float4 v7 = *(const float4*)(wvT + 7 * (NN * 4) + jc * 256);

        float cr6 = crp[jc * 64 + lane];
        float dA = 0.f, dB = 0.f;
        #pragma unroll
        for (int dq = 0; dq < 8; dq++) {
            float4 w4 = *(const float4*)(wrT + dq * (NN * 4) + jc * 256);
            dA = fmaf(att_r[dq*4+0], fabsf(wlA[dq*4+0] + w4.x), dA);
            dB = fmaf(att_r[dq*4+0], fabsf(wlB[dq*4+0] + w4.x), dB);
            dA = fmaf(att_r[dq*4+1], fabsf(wlA[dq*4+1] + w4.y), dA);
            dB = fmaf(att_r[dq*4+1], fabsf(wlB[dq*4+1] + w4.y), dB);
            dA = fmaf(att_r[dq*4+2], fabsf(wlA[dq*4+2] + w4.z), dA);
            dB = fmaf(att_r[dq*4+2], fabsf(wlB[dq*4+2] + w4.z), dB);
            dA = fmaf(att_r[dq*4+3], fabsf(wlA[dq*4+3] + w4.w), dA);
            dB = fmaf(att_r[dq*4+3], fabsf(wlB[dq*4+3] + w4.w), dB);
        }
        float eA = (clA + cr6) + dA; eA = ((mbA >> jc) & 1u) ? eA : -1e9f;
        float eB = (clB + cr6) + dB; eB = ((mbB >> jc) & 1u) ? eB : -1e9f;

        // deferred rescale: triggers rarely (first edge + genuine max jumps)
        if (eA > mA + 8.0f) {
            float sc = __expf(mA - eA);       // 0 on first trigger
            lsA *= sc;
            #pragma unroll
            for (int d = 0; d < 32; d++) accA[d] *= sc;
            mA = eA;
        }
        if (eB > mB + 8.0f) {
            float sc = __expf(mB - eB);
            lsB *= sc;
            #pragma unroll
            for (int d = 0; d < 32; d++) accB[d] *= sc;
            mB = eB;
        }
        float peA = __expf(eA - mA);          // masked: exp(-1e9-m) = exact 0
        float peB = __expf(eB - mB);
        lsA += peA; lsB += peB;

        accA[0]  = fmaf(peA, v0.x, accA[0]);  accB[0]  = fmaf(peB, v0.x, accB[0]);
        accA[1]  = fmaf(peA, v0.y, accA[1]);  accB[1]  = fmaf(peB, v0.y, accB[1]);
        accA[2]  = fmaf(peA, v0.z, accA[2]);  accB[2]  = fmaf(peB, v0.z, accB[2]);
        accA[3]  = fmaf(peA, v0.w, accA[3]);  accB[3]  = fmaf(peB, v0.w, accB[3]);
        accA[4]  = fmaf(peA, v1.x, accA[4]);  accB[4]  = fmaf(peB, v1.x, accB[4]);
        accA[5]  = fmaf(peA, v1.y, accA[5]);  accB[5]  = fmaf(peB, v1.y, accB[5]);
        accA[6]  = fmaf(peA, v1.z, accA[6]);  accB[6]  = fmaf(peB, v1.z, accB[6]);
        accA[7]  = fmaf(peA, v1.w, accA[7]);  accB[7]  = fmaf(peB, v1.w, accB[7]);
        accA[8]  = fmaf(peA, v2.x, accA[8]);  accB[8]  = fmaf(peB, v2.x, accB[8]);
        accA[9]  = fmaf(peA, v2.y, accA[9]);  accB[9]  = fmaf(peB, v2.y, accB[9]);
        accA[10] = fmaf(peA, v2.z, accA[10]); accB[10] = fmaf(peB, v2.z, accB[10]);
        accA[11] = fmaf(peA, v2.w, accA[11]); accB[11] = fmaf(peB, v2.w, accB[11]);
        accA[12] = fmaf(peA, v3.x, accA[12]); accB[12] = fmaf(peB, v3.x, accB[12]);
        accA[13] = fmaf(peA, v3.y, accA[13]); accB[13] = fmaf(peB, v3.y, accB[13]);
        accA[14] = fmaf(peA, v3.z, accA[14]); accB[14] = fmaf(peB, v3.z, accB[14]);
        accA[15] = fmaf(peA, v3.w, accA[15]); accB[15] = fmaf(peB, v3.w, accB[15]);
        accA[16] = fmaf(peA, v4.x, accA[16]); accB[16] = fmaf(peB, v4.x, accB[16]);
        accA[17] = fmaf(peA, v4.y, accA[17]); accB[17] = fmaf(peB, v4.y, accB[17]);
        accA[18] = fmaf(peA, v4.z, accA[18]); accB[18] = fmaf(peB, v4.z, accB[18]);
        accA[19] = fmaf(peA, v4.w, accA[19]); accB[19] = fmaf(peB, v4.w, accB[19]);
        accA[20] = fmaf(peA, v5.x, accA[20]); accB[20] = fmaf(peB, v5.x, accB[20]);
        accA[21] = fmaf(peA, v5.y, accA[21]); accB[21] = fmaf(peB, v5.y, accB[21]);
        accA[22] = fmaf(peA, v5.z, accA[22]); accB[22] = fmaf(peB, v5.z, accB[22]);
        accA[23] = fmaf(peA, v5.w, accA[23]); accB[23] = fmaf(peB, v5.w, accB[23]);
        accA[24] = fmaf(peA, v6.x, accA[24]); accB[24] = fmaf(peB, v6.x, accB[24]);
        accA[25] = fmaf(peA, v6.y, accA[25]); accB[25] = fmaf(peB, v6.y, accB[25]);
        accA[26] = fmaf(peA, v6.z, accA[26]); accB[26] = fmaf(peB, v6.z, accB[26]);
        accA[27] = fmaf(peA, v6.w, accA[27]); accB[27] = fmaf(peB, v6.w, accB[27]);
        accA[28] = fmaf(peA, v7.x, accA[28]); accB[28] = fmaf(peB, v7.x, accB[28]);
        accA[29] = fmaf(peA, v7.y, accA[29]); accB[29] = fmaf(peB, v7.y, accB[29]);
        accA[30] = fmaf(peA, v7.z, accA[30]); accB[30] = fmaf(peB, v7.z, accB[30]);
        accA[31] = fmaf(peA, v7.w, accA[31]); accB[31] = fmaf(peB, v7.w, accB[31]);
    }

    // merge: cross-lane max, single end-rescale, cross-lane lsum
    float gA = mA, gB = mB;
    #pragma unroll
    for (int off = 32; off > 0; off >>= 1) {
        gA = fmaxf(gA, __shfl_xor(gA, off, 64));
        gB = fmaxf(gB, __shfl_xor(gB, off, 64));
    }
    float scA = __expf(mA - gA), scB = __expf(mB - gB);  // all-masked lane -> 0
    lsA *= scA; lsB *= scB;
    #pragma unroll
    for (int d = 0; d < 32; d++) { accA[d] *= scA; accB[d] *= scB; }
    #pragma unroll
    for (int off = 32; off > 0; off >>= 1) {
        lsA += __shfl_xor(lsA, off, 64);
        lsB += __shfl_xor(lsB, off, 64);
    }
    if (lane == 0) {
        invs[2 * p][h]     = 1.0f / lsA;
        invs[2 * p + 1][h] = 1.0f / lsB;
    }

    // acc cross-lane reduce via LDS, 2 rounds (node = 2p + r); region = p*4+h
    float* rbuf = &rbuf_s[0][0][0];
    {   // round r=0: node iA
        int reg = p * 4 + h;
        #pragma unroll
        for (int d = 0; d < 32; d++) rbuf[(reg * 64 + lane) * 33 + d] = accA[d];
        __syncthreads();
        int g = t >> 6, d = lane & 31, half = lane >> 5;
        float s = 0.0f;
        #pragma unroll
        for (int lq = 0; lq < 32; lq++) s += rbuf[(g * 64 + half * 32 + lq) * 33 + d];
        s += __shfl_xor(s, 32, 64);
        int node = 2 * (g >> 2), hh = g & 3;
        if (half == 0) agg_s[node][hh * 32 + d] = s * invs[node][hh];
        __syncthreads();
    }
    {   // round r=1: node iB
        int reg = p * 4 + h;
        #pragma unroll
        for (int d = 0; d < 32; d++) rbuf[(reg * 64 + lane) * 33 + d] = accB[d];
        __syncthreads();
        int g = t >> 6, d = lane & 31, half = lane >> 5;
        float s = 0.0f;
        #pragma unroll
        for (int lq = 0; lq < 32; lq++) s += rbuf[(g * 64 + half * 32 + lq) * 33 + d];
        s += __shfl_xor(s, 32, 64);
        int node = 2 * (g >> 2) + 1, hh = g & 3;
        if (half == 0) agg_s[node][hh * 32 + d] = s * invs[node][hh];
        __syncthreads();
    }

    // layernorm + residual for the 4 nodes: t -> node n=t>>7, feature f=t&127
    {
        int n = t >> 7, f = t & 127;
        float agg = agg_s[n][f];
        float s = agg, s2 = agg * agg;
        #pragma unroll
        for (int off = 32; off > 0; off >>= 1) {
            s  += __shfl_xor(s,  off, 64);
            s2 += __shfl_xor(s2, off, 64);
        }
        int half = (t >> 6) & 1;
        if (lane == 0) { red2[n][half][0] = s; red2[n][half][1] = s2; }
        __syncthreads();
        float ts  = red2[n][0][0] + red2[n][1][0];
        float ts2 = red2[n][0][1] + red2[n][1][1];
        float mu  = ts  * (1.0f / HID);
        float var = ts2 * (1.0f / HID) - mu * mu;
        float gm = ws[OFF_GAM + l * HID + f];
        float be = ws[OFF_BET + l * HID + f];
        float o = (agg - mu) * rsqrtf(var + 1e-5f) * gm + be;
        ws[OFF_H + (i0 + n) * HID + f] += fmaxf(o, 0.0f);
    }
}

// ---- fused epilogue, 1024 threads/block ----
// blocks 0..63: node_logits + delta_mu heads, 16 nodes/block (wave = node).
// block 64: pooled mean (8 row-groups x 128 rows, unroll-16 ILP) + value head.
__global__ __launch_bounds__(1024) void k_post(float* ws, const unsigned* nf, void* out) {
    bool bf = detect_bf(nf);
    int b = blockIdx.x, t = threadIdx.x;
    if (b < 64) {
        __shared__ float hrow[16][HID];
        int n = t >> 6, tt = t & 63;
        int i = b * 16 + n;
        hrow[n][tt]      = ws[OFF_H + i * HID + tt];
        hrow[n][tt + 64] = ws[OFF_H + i * HID + tt + 64];
        __syncthreads();
        const float* Wn1 = ws + OFF_WN1;
        const float* Wd1 = ws + OFF_WD1;
        float z1 = ws[OFF_BN1 + tt], zd = ws[OFF_BD1 + tt];
        #pragma unroll 4
        for (int k = 0; k < HID; k++) {
            float hk = hrow[n][k];
            z1 += hk * Wn1[k * 64 + tt];
            zd += hk * Wd1[k * 64 + tt];
        }
        z1 = fmaxf(z1, 0.0f); zd = fmaxf(zd, 0.0f);
        float lg = z1 * ws[OFF_WN2 + tt];
        float d0 = zd * ws[OFF_WD2 + tt * 2 + 0];
        float d1 = zd * ws[OFF_WD2 + tt * 2 + 1];
        #pragma unroll
        for (int off = 32; off > 0; off >>= 1) {
            lg += __shfl_xor(lg, off, 64);
            d0 += __shfl_xor(d0, off, 64);
            d1 += __shfl_xor(d1, off, 64);
        }
        if (tt == 0) {
            store_out(out, i,              lg + ws[OFF_BN2],     bf);
            store_out(out, NN + i * 2 + 0, d0 + ws[OFF_BD2 + 0], bf);
            store_out(out, NN + i * 2 + 1, d1 + ws[OFF_BD2 + 1], bf);
        }
    } else {
        __shared__ float part[8][HID];
        __shared__ float pooled[HID];
        int g = t >> 7, c = t & 127;
        float s = 0.0f;
        #pragma unroll 16
        for (int r = 0; r < 128; r++) s += ws[OFF_H + (g * 128 + r) * HID + c];
        part[g][c] = s;
        __syncthreads();
        if (t < HID) {
            float p = 0.0f;
            #pragma unroll
            for (int gg = 0; gg < 8; gg++) p += part[gg][t];
            pooled[t] = p * (1.0f / NN);
        }
        __syncthreads();
        if (t < 64) {
            float z = ws[OFF_BV1 + t];
            float z1 = 0.0f;
            #pragma unroll 8
            for (int k = 0; k < HID; k += 2) {
                z  += pooled[k]     * ws[OFF_WV1 + k * 64 + t];
                z1 += pooled[k + 1] * ws[OFF_WV1 + (k + 1) * 64 + t];
            }
            z = fmaxf(z + z1, 0.0f);
            float pv = z * ws[OFF_WV2 + t];
            #pragma unroll
            for (int off = 32; off > 0; off >>= 1) pv += __shfl_xor(pv, off, 64);
            if (t == 0) store_out(out, 3072, pv + ws[OFF_BV2], bf);
        }
    }
}

extern "C" void kernel_launch(void* const* d_in, const int* in_sizes, int n_in,
                              void* d_out, int out_size, void* d_ws, size_t ws_size,
                              hipStream_t stream) {
    float* ws = (float*)d_ws;
    const unsigned* nf = (const unsigned*)d_in[0];

    P21 ptrs;
    const int map[21] = {0,2,3,4,5,6,7,8,9,10,11,12,13,14,15,16,17,18,19,20,21};
    for (int s = 0; s < 21; s++) ptrs.p[s] = d_in[map[s]];

    // prologue: convert (CB blocks) | mask (NN blocks) | h0 (NN/2 blocks)
    k_pre<<<CB + NN + NN / 2, 256, 0, stream>>>(ptrs, d_in[1], nf, ws);

    for (int l = 0; l < NL; l++) {
        k_mm3<<<dim3(NN / 4, 3), 128, 0, stream>>>(ws, l);
        k_attn<<<NN / 4, 512, 0, stream>>>(ws, l);
    }

    k_post<<<65, 1024, 0, stream>>>(ws, nf, d_out);
}